// Round 12
// baseline (456.043 us; speedup 1.0000x reference)
//
#include <hip/hip_runtime.h>
#include <hip/hip_bf16.h>
#include <math.h>

#define HIDDEN   1024
#define HEADS    16
#define HEAD_DIM 64
#define BATCH    4
#define SEQ      4096
#define M_TOTAL  (BATCH * SEQ)          // 16384
#define M_HALF   8192
#define FFT_N    4096
#define WSZ      ((size_t)HIDDEN * HIDDEN)
#define PI2      6.28318530717958647692f

typedef _Float16 f16x8 __attribute__((ext_vector_type(8)));   // 8 fp16 = 4 VGPR (MFMA A/B frag)
typedef float    f32x4 __attribute__((ext_vector_type(4)));   // MFMA C/D frag

#if defined(__has_builtin)
#if __has_builtin(__builtin_amdgcn_global_load_lds)
#define HAVE_GLL 1
#else
#define HAVE_GLL 0
#endif
#else
#define HAVE_GLL 0
#endif

#if HAVE_GLL
// async global->LDS, 16B/lane. dest = wave-uniform base + lane*16 (linear in slot).
__device__ __forceinline__ void gload16(const void* g, void* l) {
    __builtin_amdgcn_global_load_lds(
        (const __attribute__((address_space(1))) unsigned int*)g,
        (__attribute__((address_space(3))) unsigned int*)l,
        16, 0, 0);
}
#endif

// fp16 one-sided split: v = hi + lo + O(2^-22 |v|)   (identical math to r11)
__device__ __forceinline__ void split8_f16(float4 v0, float4 v1,
                                           ushort* __restrict__ hd,
                                           ushort* __restrict__ ld) {
    const float vv[8] = {v0.x, v0.y, v0.z, v0.w, v1.x, v1.y, v1.z, v1.w};
    f16x8 hv, lv;
    #pragma unroll
    for (int e = 0; e < 8; ++e) {
        const _Float16 h = (_Float16)vv[e];
        hv[e] = h;
        lv[e] = (_Float16)(vv[e] - (float)h);
    }
    *(f16x8*)hd = hv;
    *(f16x8*)ld = lv;
}

__device__ __forceinline__ void cvt8_f16(float4 v0, float4 v1,
                                         ushort* __restrict__ d) {
    const float vv[8] = {v0.x, v0.y, v0.z, v0.w, v1.x, v1.y, v1.z, v1.w};
    f16x8 hv;
    #pragma unroll
    for (int e = 0; e < 8; ++e) hv[e] = (_Float16)vv[e];
    *(f16x8*)d = hv;
}

// scalar fp16 split (transpose kernel, validated r10/r11 math)
__device__ __forceinline__ void split1_f16(float v, ushort& h, ushort& l) {
    const _Float16 hh = (_Float16)v;
    const _Float16 ll = (_Float16)(v - (float)hh);
    union { _Float16 f; ushort u; } ch, cl;
    ch.f = hh; cl.f = ll;
    h = ch.u; l = cl.u;
}

// ---------------------------------------------------------------------------
// Pre-pass kernels: fp32 -> fp16 hi/lo split, and fp32 -> fp16 single cvt.
// 8 elems/thread; grids are exact multiples.
// ---------------------------------------------------------------------------
__global__ __launch_bounds__(256) void split16_kernel(
    const float* __restrict__ src, ushort* __restrict__ h,
    ushort* __restrict__ l)
{
    const size_t i = ((size_t)blockIdx.x * 256 + threadIdx.x) * 8;
    float4 v0 = *(const float4*)(src + i);
    float4 v1 = *(const float4*)(src + i + 4);
    split8_f16(v0, v1, h + i, l + i);
}

__global__ __launch_bounds__(256) void cvt16_kernel(
    const float* __restrict__ src, ushort* __restrict__ h)
{
    const size_t i = ((size_t)blockIdx.x * 256 + threadIdx.x) * 8;
    float4 v0 = *(const float4*)(src + i);
    float4 v1 = *(const float4*)(src + i + 4);
    cvt8_f16(v0, v1, h + i);
}

// ---------------------------------------------------------------------------
// QKV GEMM (MFMA fp16, pure gload16 staging): per batch-half.
//   ct[p][n][mh] = sum_k (Wh+Wl)[ng][k] * xh[mbase+mh][k]
// 256x256 tile, 1024 thr / 16 waves (4r x 4c), BK=32, dbuf 96 KiB.
// All operands pre-converted fp16 in HBM -> staging = 3 gload16/thread,
// zero VALU, zero regs (Common-mistake #1 lever; rule #21 layout:
// linear LDS dest + inverse-swizzled source chunk + swizzled read).
// r9/r11-validated schedule, swizzle, epilogue; product-major 2-product.
// ---------------------------------------------------------------------------
__global__ __launch_bounds__(1024, 1) void gemm_qkv_mfma6(
    const ushort* __restrict__ xh,
    const ushort* __restrict__ wh, const ushort* __restrict__ wl,
    const float* __restrict__ bq, const float* __restrict__ bk,
    const float* __restrict__ bv,
    float* __restrict__ qkvt, int mbase)
{
    __shared__ ushort Ah[2][8192], Al[2][8192];   // W tile [256n][32k] hi/lo fp16
    __shared__ ushort Bh[2][8192];                // x tile [256m][32k] fp16 (96 KiB)

    const int tid  = threadIdx.x;
    const int lane = tid & 63;
    const int wid  = tid >> 6;
    const int wr   = wid >> 2;        // n-dim wave 0..3
    const int wc   = wid & 3;         // m-dim wave 0..3
    const int m0   = blockIdx.x * 256;            // within half [0,8192)
    const int ng0  = blockIdx.y * 256;            // stacked n in [0,3072)
    const int p    = ng0 >> 10;
    const int n0p  = ng0 & 1023;

    const float* __restrict__ bias = (p == 0) ? bq : (p == 1 ? bk : bv);
    float* __restrict__ ct = qkvt + (size_t)p * HIDDEN * M_HALF;

    const int row = tid >> 2;         // [0,256)
    const int chS = (tid & 3) ^ ((row >> 1) & 3);   // inverse-swizzled source chunk

    const int fr = lane & 15;
    const int fc = lane >> 4;
    const int cc = (fc ^ ((fr >> 1) & 3)) * 8;

    f32x4 acc[4][4];
    #pragma unroll
    for (int rf = 0; rf < 4; ++rf)
        #pragma unroll
        for (int cf = 0; cf < 4; ++cf)
            acc[rf][cf] = (f32x4){0.f, 0.f, 0.f, 0.f};

#if HAVE_GLL
    #define QKV_STAGE(K0, BUF) {                                                   \
        const size_t gw = (size_t)(ng0 + row) * HIDDEN + (K0) + (size_t)chS * 8;   \
        const size_t gx = (size_t)(mbase + m0 + row) * HIDDEN + (K0) + (size_t)chS * 8; \
        gload16(wh + gw, &Ah[BUF][(size_t)tid * 8]);                               \
        gload16(wl + gw, &Al[BUF][(size_t)tid * 8]);                               \
        gload16(xh + gx, &Bh[BUF][(size_t)tid * 8]);                               \
    }
#else
    #define QKV_STAGE(K0, BUF) {                                                   \
        const size_t gw = (size_t)(ng0 + row) * HIDDEN + (K0) + (size_t)chS * 8;   \
        const size_t gx = (size_t)(mbase + m0 + row) * HIDDEN + (K0) + (size_t)chS * 8; \
        *(f16x8*)&Ah[BUF][(size_t)tid * 8] = *(const f16x8*)(wh + gw);             \
        *(f16x8*)&Al[BUF][(size_t)tid * 8] = *(const f16x8*)(wl + gw);             \
        *(f16x8*)&Bh[BUF][(size_t)tid * 8] = *(const f16x8*)(xh + gx);             \
    }
#endif

    QKV_STAGE(0, 0);
    __syncthreads();

    for (int ks = 0; ks < HIDDEN / 32; ++ks) {
        const int cur = ks & 1;
        if (ks + 1 < HIDDEN / 32) { QKV_STAGE((ks + 1) * 32, cur ^ 1); }

        {   // compute(cur): 32 MFMA / wave, product-major (r11-validated)
            const ushort* pAh = Ah[cur];
            const ushort* pAl = Al[cur];
            const ushort* pBh = Bh[cur];
            f16x8 a_h[4], a_l[4], b_h[4];
            #pragma unroll
            for (int rf = 0; rf < 4; ++rf) {
                const int R = wr * 64 + rf * 16 + fr;
                a_h[rf] = *(const f16x8*)(pAh + R * 32 + cc);
                a_l[rf] = *(const f16x8*)(pAl + R * 32 + cc);
            }
            #pragma unroll
            for (int cf = 0; cf < 4; ++cf) {
                const int R = wc * 64 + cf * 16 + fr;
                b_h[cf] = *(const f16x8*)(pBh + R * 32 + cc);
            }
            #pragma unroll
            for (int rf = 0; rf < 4; ++rf)
                #pragma unroll
                for (int cf = 0; cf < 4; ++cf)
                    acc[rf][cf] = __builtin_amdgcn_mfma_f32_16x16x32_f16(a_h[rf], b_h[cf], acc[rf][cf], 0, 0, 0);
            #pragma unroll
            for (int rf = 0; rf < 4; ++rf)
                #pragma unroll
                for (int cf = 0; cf < 4; ++cf)
                    acc[rf][cf] = __builtin_amdgcn_mfma_f32_16x16x32_f16(a_l[rf], b_h[cf], acc[rf][cf], 0, 0, 0);
        }
        __syncthreads();
    }
    #undef QKV_STAGE

    // epilogue (validated mapping): row n_local = wr*64+rf*16+rq*4+r ; col m = wc*64+cf*16+fr
    const int rq = lane >> 4;
    #pragma unroll
    for (int rf = 0; rf < 4; ++rf) {
        #pragma unroll
        for (int r = 0; r < 4; ++r) {
            const int nl = wr * 64 + rf * 16 + rq * 4 + r;
            const float bv = bias[n0p + nl];
            float* dst = ct + (size_t)(n0p + nl) * M_HALF + m0 + wc * 64;
            #pragma unroll
            for (int cf = 0; cf < 4; ++cf)
                dst[cf * 16 + fr] = acc[rf][cf][r] + bv;
        }
    }
}

// ---------------------------------------------------------------------------
// Radix-16 FFT machinery (math UNCHANGED, validated r5-r11; indexing is now
// per batch-half: planes are [1024][8192], 2048 blocks/half).
// ---------------------------------------------------------------------------
__device__ __forceinline__ float2 cmul(float2 a, float2 b) {
    return {a.x*b.x - a.y*b.y, a.x*b.y + a.y*b.x};
}

__device__ __forceinline__ int phys(int p) { return p ^ ((p >> 4) & 15); }

template<int DIR>
__device__ __forceinline__ void dft16(const float2* x, float2* X) {
    float2 t[16];
    #pragma unroll
    for (int n0 = 0; n0 < 4; ++n0) {
        float2 a = x[n0], b = x[n0+4], c = x[n0+8], d = x[n0+12];
        float2 s0 = {a.x+c.x, a.y+c.y}, s1 = {a.x-c.x, a.y-c.y};
        float2 s2 = {b.x+d.x, b.y+d.y}, s3 = {b.x-d.x, b.y-d.y};
        t[n0*4+0] = {s0.x+s2.x, s0.y+s2.y};
        t[n0*4+2] = {s0.x-s2.x, s0.y-s2.y};
        if (DIR < 0) {
            t[n0*4+1] = {s1.x+s3.y, s1.y-s3.x};
            t[n0*4+3] = {s1.x-s3.y, s1.y+s3.x};
        } else {
            t[n0*4+1] = {s1.x-s3.y, s1.y+s3.x};
            t[n0*4+3] = {s1.x+s3.y, s1.y-s3.x};
        }
    }
    const float C1 = 0.92387953251128674f;
    const float S1_ = 0.38268343236508978f;
    const float R2 = 0.70710678118654752f;
    #define TW(idx, cc_, ss_) t[idx] = cmul(t[idx], (float2){cc_, DIR*(ss_)})
    TW(1*4+1, C1, S1_);   TW(1*4+2, R2, R2);    TW(1*4+3, S1_, C1);
    TW(2*4+1, R2, R2);    TW(2*4+2, 0.f, 1.f);  TW(2*4+3, -R2, R2);
    TW(3*4+1, S1_, C1);   TW(3*4+2, -R2, R2);   TW(3*4+3, -C1, -S1_);
    #undef TW
    #pragma unroll
    for (int k0 = 0; k0 < 4; ++k0) {
        float2 a = t[0+k0], b = t[4+k0], c = t[8+k0], d = t[12+k0];
        float2 s0 = {a.x+c.x, a.y+c.y}, s1 = {a.x-c.x, a.y-c.y};
        float2 s2 = {b.x+d.x, b.y+d.y}, s3 = {b.x-d.x, b.y-d.y};
        X[k0+0]  = {s0.x+s2.x, s0.y+s2.y};
        X[k0+8]  = {s0.x-s2.x, s0.y-s2.y};
        if (DIR < 0) {
            X[k0+4]  = {s1.x+s3.y, s1.y-s3.x};
            X[k0+12] = {s1.x-s3.y, s1.y+s3.x};
        } else {
            X[k0+4]  = {s1.x-s3.y, s1.y+s3.x};
            X[k0+12] = {s1.x+s3.y, s1.y-s3.x};
        }
    }
}

__device__ __forceinline__ void twiddle_apply(float2* y, float ang) {
    float s, c;
    __sincosf(ang, &s, &c);
    const float2 base = {c, s};
    float2 w = base;
    #pragma unroll
    for (int u = 1; u < 16; ++u) {
        y[u] = cmul(y[u], w);
        w = cmul(w, base);
    }
}

__global__ __launch_bounds__(256) void fft_attn_kernel(
    const float* __restrict__ qt, const float* __restrict__ kt,
    const float* __restrict__ vt, float* __restrict__ ot_h)
{
    __shared__ float2 bufA[FFT_N];
    __shared__ float2 bufB[FFT_N];

    const int tid  = threadIdx.x;
    const int bid  = blockIdx.x;      // [0, 2048)
    const int n    = bid >> 1;
    const int bloc = bid & 1;

    const size_t off = (size_t)n * M_HALF + (size_t)bloc * SEQ;
    const float* qrow = qt + off;
    const float* krow = kt + off;
    const float* vrow = vt + off;
    float*       orow = ot_h + off;

    {
        const int q = tid;
        float2 xA[16], xB[16], yA[16], yB[16];
        #pragma unroll
        for (int r = 0; r < 16; ++r) {
            xA[r] = { qrow[q + 256*r], krow[q + 256*r] };
            xB[r] = { vrow[q + 256*r], 0.f };
        }
        dft16<-1>(xA, yA);
        dft16<-1>(xB, yB);
        const float ang = -PI2 * (float)q / 4096.f;
        twiddle_apply(yA, ang);
        twiddle_apply(yB, ang);
        #pragma unroll
        for (int u = 0; u < 16; ++u) {
            bufA[phys(q + 256*u)] = yA[u];
            bufB[phys(q + 256*u)] = yB[u];
        }
    }
    __syncthreads();
    {
        const int blk = tid >> 4, a = tid & 15;
        const int base = 256*blk + a;
        float2 xA[16], xB[16], yA[16], yB[16];
        #pragma unroll
        for (int c = 0; c < 16; ++c) {
            xA[c] = bufA[phys(base + 16*c)];
            xB[c] = bufB[phys(base + 16*c)];
        }
        dft16<-1>(xA, yA);
        dft16<-1>(xB, yB);
        const float ang = -PI2 * (float)a / 256.f;
        twiddle_apply(yA, ang);
        twiddle_apply(yB, ang);
        #pragma unroll
        for (int c = 0; c < 16; ++c) {
            bufA[phys(base + 16*c)] = yA[c];
            bufB[phys(base + 16*c)] = yB[c];
        }
    }
    __syncthreads();
    {
        const int blk = tid >> 4, c = tid & 15;
        const int base = 256*blk + 16*c;
        float2 xA[16], xB[16], yA[16], yB[16];
        #pragma unroll
        for (int a2 = 0; a2 < 16; ++a2) {
            xA[a2] = bufA[phys(base + a2)];
            xB[a2] = bufB[phys(base + a2)];
        }
        dft16<-1>(xA, yA);
        dft16<-1>(xB, yB);
        #pragma unroll
        for (int d = 0; d < 16; ++d) {
            bufA[phys(base + d)] = yA[d];
            bufB[phys(base + d)] = yB[d];
        }
    }
    __syncthreads();
    #pragma unroll
    for (int it = 0; it < 16; ++it) {
        const int p  = tid + it * 256;
        const int j  = ((p & 15) << 8) | (p & 0xF0) | (p >> 8);
        const int jn = (FFT_N - j) & (FFT_N - 1);
        const int pn = ((jn & 15) << 8) | (jn & 0xF0) | (jn >> 8);
        const float2 Zj = bufA[phys(p)];
        const float2 Zn = bufA[phys(pn)];
        const float2 Q = { 0.5f*(Zj.x + Zn.x), 0.5f*(Zj.y - Zn.y) };
        const float2 K = { 0.5f*(Zj.y + Zn.y), -0.5f*(Zj.x - Zn.x) };
        const float2 G = { Q.x*K.x + Q.y*K.y, Q.y*K.x - Q.x*K.y };
        const float2 V = bufB[phys(p)];
        bufB[phys(p)] = { G.x*V.x - G.y*V.y, G.x*V.y + G.y*V.x };
    }
    __syncthreads();
    {
        const int blk = tid >> 4, c = tid & 15;
        const int base = 256*blk + 16*c;
        float2 x[16], y[16];
        #pragma unroll
        for (int d = 0; d < 16; ++d) x[d] = bufB[phys(base + d)];
        dft16<1>(x, y);
        #pragma unroll
        for (int p0 = 0; p0 < 16; ++p0) bufB[phys(base + p0)] = y[p0];
    }
    __syncthreads();
    {
        const int blk = tid >> 4, p0 = tid & 15;
        const int base = 256*blk + p0;
        float2 x[16], y[16];
        #pragma unroll
        for (int c = 0; c < 16; ++c) x[c] = bufB[phys(base + 16*c)];
        twiddle_apply(x, PI2 * (float)p0 / 256.f);
        dft16<1>(x, y);
        #pragma unroll
        for (int p1 = 0; p1 < 16; ++p1) bufB[phys(base + 16*p1)] = y[p1];
    }
    __syncthreads();
    {
        const int qq = tid;
        float2 x[16], y[16];
        #pragma unroll
        for (int t = 0; t < 16; ++t) x[t] = bufB[phys(qq + 256*t)];
        twiddle_apply(x, PI2 * (float)qq / 4096.f);
        dft16<1>(x, y);
        const float scale = 0.125f / 4096.f;
        #pragma unroll
        for (int p2 = 0; p2 < 16; ++p2)
            orow[qq + 256*p2] = y[p2].x * scale;
    }
}

// ---------------------------------------------------------------------------
// Transpose + fp16 split: ot fp32 [half][n][8192] -> oth/otl fp16 [m][k=n]
// (r11-validated math; src indexing adapted to the half-plane layout)
// ---------------------------------------------------------------------------
__global__ __launch_bounds__(256) void transpose_split_kernel(
    const float* __restrict__ ot, ushort* __restrict__ oth,
    ushort* __restrict__ otl)
{
    __shared__ float tile[64][65];
    const int tid = threadIdx.x;
    const int m0  = blockIdx.x * 64;      // global m
    const int n0  = blockIdx.y * 64;
    const int r   = tid >> 4;
    const int c   = tid & 15;

    const int h   = m0 >> 13;             // batch half
    const int ml0 = m0 & (M_HALF - 1);
    const float* src = ot + (size_t)h * HIDDEN * M_HALF;

    #pragma unroll
    for (int rr = 0; rr < 4; ++rr) {
        const int nl = r + rr * 16;
        float4 v = *(const float4*)(src + (size_t)(n0 + nl) * M_HALF + ml0 + c * 4);
        tile[nl][c * 4 + 0] = v.x; tile[nl][c * 4 + 1] = v.y;
        tile[nl][c * 4 + 2] = v.z; tile[nl][c * 4 + 3] = v.w;
    }
    __syncthreads();
    #pragma unroll
    for (int rr = 0; rr < 4; ++rr) {
        const int ml = r + rr * 16;
        ushort4 hh, ll;
        split1_f16(tile[c * 4 + 0][ml], hh.x, ll.x);
        split1_f16(tile[c * 4 + 1][ml], hh.y, ll.y);
        split1_f16(tile[c * 4 + 2][ml], hh.z, ll.z);
        split1_f16(tile[c * 4 + 3][ml], hh.w, ll.w);
        *(ushort4*)(oth + (size_t)(m0 + ml) * HIDDEN + n0 + c * 4) = hh;
        *(ushort4*)(otl + (size_t)(m0 + ml) * HIDDEN + n0 + c * 4) = ll;
    }
}

// ---------------------------------------------------------------------------
// Output GEMM (MFMA fp16, pure gload16 staging): out[m][n] =
//   (oth+otl)[m][:] . woh[n][:] + bo[n].  Same structure as qkv.
// ---------------------------------------------------------------------------
__global__ __launch_bounds__(1024, 1) void gemm_out_mfma6(
    const ushort* __restrict__ oth, const ushort* __restrict__ otl,
    const ushort* __restrict__ woh, const float* __restrict__ bo,
    float* __restrict__ out)
{
    __shared__ ushort Ah[2][8192], Al[2][8192];   // ot^T tile [256m][32k] hi/lo fp16
    __shared__ ushort Bh[2][8192];                // Wo tile [256n][32k] fp16

    const int tid  = threadIdx.x;
    const int lane = tid & 63;
    const int wid  = tid >> 6;
    const int wr   = wid >> 2;        // m-dim wave
    const int wc   = wid & 3;         // n-dim wave
    const int m0   = blockIdx.x * 256;
    const int n0   = blockIdx.y * 256;

    const int row = tid >> 2;
    const int chS = (tid & 3) ^ ((row >> 1) & 3);

    const int fr = lane & 15;
    const int fc = lane >> 4;
    const int cc = (fc ^ ((fr >> 1) & 3)) * 8;

    f32x4 acc[4][4];
    #pragma unroll
    for (int rf = 0; rf < 4; ++rf)
        #pragma unroll
        for (int cf = 0; cf < 4; ++cf)
            acc[rf][cf] = (f32x4){0.f, 0.f, 0.f, 0.f};

#if HAVE_GLL
    #define OUT_STAGE(K0, BUF) {                                                   \
        const size_t ga = (size_t)(m0 + row) * HIDDEN + (K0) + (size_t)chS * 8;    \
        const size_t gb = (size_t)(n0 + row) * HIDDEN + (K0) + (size_t)chS * 8;    \
        gload16(oth + ga, &Ah[BUF][(size_t)tid * 8]);                              \
        gload16(otl + ga, &Al[BUF][(size_t)tid * 8]);                              \
        gload16(woh + gb, &Bh[BUF][(size_t)tid * 8]);                              \
    }
#else
    #define OUT_STAGE(K0, BUF) {                                                   \
        const size_t ga = (size_t)(m0 + row) * HIDDEN + (K0) + (size_t)chS * 8;    \
        const size_t gb = (size_t)(n0 + row) * HIDDEN + (K0) + (size_t)chS * 8;    \
        *(f16x8*)&Ah[BUF][(size_t)tid * 8] = *(const f16x8*)(oth + ga);            \
        *(f16x8*)&Al[BUF][(size_t)tid * 8] = *(const f16x8*)(otl + ga);            \
        *(f16x8*)&Bh[BUF][(size_t)tid * 8] = *(const f16x8*)(woh + gb);            \
    }
#endif

    OUT_STAGE(0, 0);
    __syncthreads();

    for (int ks = 0; ks < HIDDEN / 32; ++ks) {
        const int cur = ks & 1;
        if (ks + 1 < HIDDEN / 32) { OUT_STAGE((ks + 1) * 32, cur ^ 1); }

        {
            const ushort* pAh = Ah[cur];
            const ushort* pAl = Al[cur];
            const ushort* pBh = Bh[cur];
            f16x8 a_h[4], a_l[4], b_h[4];
            #pragma unroll
            for (int rf = 0; rf < 4; ++rf) {
                const int R = wr * 64 + rf * 16 + fr;
                a_h[rf] = *(const f16x8*)(pAh + R * 32 + cc);
                a_l[rf] = *(const f16x8*)(pAl + R * 32 + cc);
            }
            #pragma unroll
            for (int cf = 0; cf < 4; ++cf) {
                const int R = wc * 64 + cf * 16 + fr;
                b_h[cf] = *(const f16x8*)(pBh + R * 32 + cc);
            }
            #pragma unroll
            for (int rf = 0; rf < 4; ++rf)
                #pragma unroll
                for (int cf = 0; cf < 4; ++cf)
                    acc[rf][cf] = __builtin_amdgcn_mfma_f32_16x16x32_f16(a_h[rf], b_h[cf], acc[rf][cf], 0, 0, 0);
            #pragma unroll
            for (int rf = 0; rf < 4; ++rf)
                #pragma unroll
                for (int cf = 0; cf < 4; ++cf)
                    acc[rf][cf] = __builtin_amdgcn_mfma_f32_16x16x32_f16(a_l[rf], b_h[cf], acc[rf][cf], 0, 0, 0);
        }
        __syncthreads();
    }
    #undef OUT_STAGE

    // epilogue: D row m_local = wr*64+rf*16+rq*4+r ; col n_local = wc*64+cf*16+fr
    const int rq = lane >> 4;
    float bo_v[4];
    #pragma unroll
    for (int cf = 0; cf < 4; ++cf) bo_v[cf] = bo[n0 + wc * 64 + cf * 16 + fr];
    #pragma unroll
    for (int rf = 0; rf < 4; ++rf) {
        #pragma unroll
        for (int r = 0; r < 4; ++r) {
            const int ml = wr * 64 + rf * 16 + rq * 4 + r;
            float* dst = out + (size_t)(m0 + ml) * HIDDEN + n0 + wc * 64;
            #pragma unroll
            for (int cf = 0; cf < 4; ++cf)
                dst[cf * 16 + fr] = acc[rf][cf][r] + bo_v[cf];
        }
    }
}

// ---------------------------------------------------------------------------
// Workspace layout (fits guaranteed 201.3 MB; peak 182.5 MB):
//   [0]          qkvt: fp32 [3][1024][8192] half-planes   100.66 MB
//   [100.66M]    ot:   fp32 [2][1024][8192]                67.11 MB
//                  (ot half1 region doubles as xh fp16 [16384][1024] until fft1)
//   [167.77M]    wh:   fp16 [3][1024][1024]                 6.29 MB
//   [174.06M]    wl:   fp16 [3][1024][1024]                 6.29 MB
//   [180.36M]    woh:  fp16 [1024][1024]                    2.10 MB
//   oth/otl alias qkvt region after fft1 (67.1 <= 100.66 MB).
// Order: cvt x->xh | split W | qkv0 | fft0 | qkv1 | fft1(overwrites xh) |
//        transpose(->qkvt region) | gemm_out.
// ---------------------------------------------------------------------------
extern "C" void kernel_launch(void* const* d_in, const int* in_sizes, int n_in,
                              void* d_out, int out_size, void* d_ws, size_t ws_size,
                              hipStream_t stream)
{
    const float* x  = (const float*)d_in[0];
    const float* Wq = (const float*)d_in[1];
    const float* bq = (const float*)d_in[2];
    const float* Wk = (const float*)d_in[3];
    const float* bk = (const float*)d_in[4];
    const float* Wv = (const float*)d_in[5];
    const float* bv = (const float*)d_in[6];
    const float* Wo = (const float*)d_in[7];
    const float* bo = (const float*)d_in[8];
    float* out = (float*)d_out;

    const size_t plane_h = (size_t)HIDDEN * M_HALF;   // 8.39M elements
    char* base = (char*)d_ws;
    float* qkvt = (float*)base;                               // 3 half-planes fp32
    float* ot   = (float*)(base + 3 * plane_h * 4);           // [2][1024][8192] fp32
    float* ot0  = ot;
    float* ot1  = ot + plane_h;
    ushort* xh  = (ushort*)ot1;                               // aliases ot half1 (33.55 MB exact)
    ushort* wh  = (ushort*)(base + 5 * plane_h * 4);          // stacked [3072][1024] fp16
    ushort* wl  = wh + 3 * WSZ;
    ushort* woh = wl + 3 * WSZ;
    ushort* oth = (ushort*)base;                              // alias qkvt (dead after fft1)
    ushort* otl = oth + (size_t)M_TOTAL * HIDDEN;

    // pre-passes: x -> fp16; W -> fp16 hi/lo; Wo -> fp16
    cvt16_kernel<<<(unsigned)((size_t)M_TOTAL * HIDDEN / 2048), 256, 0, stream>>>(x, xh);
    split16_kernel<<<(unsigned)(WSZ / 2048), 256, 0, stream>>>(Wq, wh, wl);
    split16_kernel<<<(unsigned)(WSZ / 2048), 256, 0, stream>>>(Wk, wh + WSZ, wl + WSZ);
    split16_kernel<<<(unsigned)(WSZ / 2048), 256, 0, stream>>>(Wv, wh + 2 * WSZ, wl + 2 * WSZ);
    cvt16_kernel<<<(unsigned)(WSZ / 2048), 256, 0, stream>>>(Wo, woh);

    // per batch-half: QKV projections then FFT attention
    for (int h = 0; h < 2; ++h) {
        gemm_qkv_mfma6<<<dim3(M_HALF / 256, 12), 1024, 0, stream>>>(
            xh, wh, wl, bq, bk, bv, qkvt, h * M_HALF);
        fft_attn_kernel<<<dim3(HIDDEN * 2), 256, 0, stream>>>(
            qkvt, qkvt + plane_h, qkvt + 2 * plane_h, h ? ot1 : ot0);
    }

    // transpose both halves -> fp16 hi/lo [m][k], then output projection
    transpose_split_kernel<<<dim3(M_TOTAL / 64, HIDDEN / 64), 256, 0, stream>>>(
        ot, oth, otl);

    gemm_out_mfma6<<<dim3(M_TOTAL / 256, HIDDEN / 256), 1024, 0, stream>>>(
        oth, otl, woh, bo, out);
}

// Round 15
// 383.339 us; speedup vs baseline: 1.1897x; 1.1897x over previous
//
#include <hip/hip_runtime.h>
#include <hip/hip_bf16.h>
#include <math.h>

#define HIDDEN   1024
#define HEADS    16
#define HEAD_DIM 64
#define BATCH    4
#define SEQ      4096
#define M_TOTAL  (BATCH * SEQ)          // 16384
#define FFT_N    4096
#define WSZ      ((size_t)HIDDEN * HIDDEN)
#define PI2      6.28318530717958647692f

typedef _Float16 f16x8 __attribute__((ext_vector_type(8)));   // 8 fp16 = 4 VGPR (MFMA A/B frag)
typedef float    f32x4 __attribute__((ext_vector_type(4)));   // MFMA C/D frag

#if defined(__has_builtin)
#if __has_builtin(__builtin_amdgcn_global_load_lds)
#define HAVE_GLL 1
#else
#define HAVE_GLL 0
#endif
#else
#define HAVE_GLL 0
#endif

#if HAVE_GLL
// async global->LDS, 16B/lane. dest = wave-uniform base + lane*16 (linear in slot).
__device__ __forceinline__ void gload16(const void* g, void* l) {
    __builtin_amdgcn_global_load_lds(
        (const __attribute__((address_space(1))) unsigned int*)g,
        (__attribute__((address_space(3))) unsigned int*)l,
        16, 0, 0);
}
#endif

// fp16 one-sided split: v = hi + lo + O(2^-22 |v|)   (r11/r12-validated math)
__device__ __forceinline__ void split8_f16(float4 v0, float4 v1,
                                           ushort* __restrict__ hd,
                                           ushort* __restrict__ ld) {
    const float vv[8] = {v0.x, v0.y, v0.z, v0.w, v1.x, v1.y, v1.z, v1.w};
    f16x8 hv, lv;
    #pragma unroll
    for (int e = 0; e < 8; ++e) {
        const _Float16 h = (_Float16)vv[e];
        hv[e] = h;
        lv[e] = (_Float16)(vv[e] - (float)h);
    }
    *(f16x8*)hd = hv;
    *(f16x8*)ld = lv;
}

__device__ __forceinline__ void cvt8_f16(float4 v0, float4 v1,
                                         ushort* __restrict__ d) {
    const float vv[8] = {v0.x, v0.y, v0.z, v0.w, v1.x, v1.y, v1.z, v1.w};
    f16x8 hv;
    #pragma unroll
    for (int e = 0; e < 8; ++e) hv[e] = (_Float16)vv[e];
    *(f16x8*)d = hv;
}

__device__ __forceinline__ void split1_f16(float v, ushort& h, ushort& l) {
    const _Float16 hh = (_Float16)v;
    const _Float16 ll = (_Float16)(v - (float)hh);
    union { _Float16 f; ushort u; } ch, cl;
    ch.f = hh; cl.f = ll;
    h = ch.u; l = cl.u;
}

// ---------------------------------------------------------------------------
// Pre-pass kernels (r12-validated)
// ---------------------------------------------------------------------------
__global__ __launch_bounds__(256) void split16_kernel(
    const float* __restrict__ src, ushort* __restrict__ h,
    ushort* __restrict__ l)
{
    const size_t i = ((size_t)blockIdx.x * 256 + threadIdx.x) * 8;
    float4 v0 = *(const float4*)(src + i);
    float4 v1 = *(const float4*)(src + i + 4);
    split8_f16(v0, v1, h + i, l + i);
}

__global__ __launch_bounds__(256) void cvt16_kernel(
    const float* __restrict__ src, ushort* __restrict__ h)
{
    const size_t i = ((size_t)blockIdx.x * 256 + threadIdx.x) * 8;
    float4 v0 = *(const float4*)(src + i);
    float4 v1 = *(const float4*)(src + i + 4);
    cvt8_f16(v0, v1, h + i);
}

// ---------------------------------------------------------------------------
// QKV GEMM (MFMA fp16, gload16 staging, TRIPLE-buffer + counted vmcnt):
//   ct[p][n][m] = sum_k (Wh+Wl)[ng][k] * xh[m][k]
// Full batch: 64 x 12 = 768 blocks = 3x256 (even rounds at 1 blk/CU).
// 1024 thr / 16 waves (4r x 4c), 256x256 tile, BK=32, LDS 144 KiB (3 slots).
// T4 schedule: per iter {wait vmcnt(3) [tile ks landed; ks+1 in flight] ->
// raw s_barrier -> compute(ks) -> STAGE(ks+2)}. Loads never drained to 0
// in the main loop (the documented 2-phase drain stall).
// Slot safety: STAGE(t) writes slot t%3, read by compute(t-3); iter t-2's
// barrier separates them. Data safety: each wave verifies its OWN 3 loads
// before the barrier; barrier publishes all (m201 mechanism).
// Compute/swizzle/epilogue byte-equivalent to r12 (passed, absmax 16).
// ---------------------------------------------------------------------------
__global__ __launch_bounds__(1024, 1) void gemm_qkv_mfma7(
    const ushort* __restrict__ xh,
    const ushort* __restrict__ wh, const ushort* __restrict__ wl,
    const float* __restrict__ bq, const float* __restrict__ bk,
    const float* __restrict__ bv,
    float* __restrict__ qkvt)
{
    __shared__ ushort Ah[3][8192], Al[3][8192];   // W tile [256n][32k] hi/lo fp16
    __shared__ ushort Bh[3][8192];                // x tile [256m][32k] fp16 (144 KiB)

    const int tid  = threadIdx.x;
    const int lane = tid & 63;
    const int wid  = tid >> 6;
    const int wr   = wid >> 2;        // n-dim wave 0..3
    const int wc   = wid & 3;         // m-dim wave 0..3
    const int m0   = blockIdx.x * 256;
    const int ng0  = blockIdx.y * 256;            // stacked n in [0,3072)
    const int p    = ng0 >> 10;
    const int n0p  = ng0 & 1023;

    const float* __restrict__ bias = (p == 0) ? bq : (p == 1 ? bk : bv);
    float* __restrict__ ct = qkvt + (size_t)p * HIDDEN * M_TOTAL;

    const int row = tid >> 2;         // [0,256)
    const int chS = (tid & 3) ^ ((row >> 1) & 3);   // inverse-swizzled source chunk

    const int fr = lane & 15;
    const int fc = lane >> 4;
    const int cc = (fc ^ ((fr >> 1) & 3)) * 8;

    f32x4 acc[4][4];
    #pragma unroll
    for (int rf = 0; rf < 4; ++rf)
        #pragma unroll
        for (int cf = 0; cf < 4; ++cf)
            acc[rf][cf] = (f32x4){0.f, 0.f, 0.f, 0.f};

#if HAVE_GLL
    #define QKV_STAGE(K0, SLOT) {                                                  \
        const size_t gw = (size_t)(ng0 + row) * HIDDEN + (K0) + (size_t)chS * 8;   \
        const size_t gx = (size_t)(m0 + row) * HIDDEN + (K0) + (size_t)chS * 8;    \
        gload16(wh + gw, &Ah[SLOT][(size_t)tid * 8]);                              \
        gload16(wl + gw, &Al[SLOT][(size_t)tid * 8]);                              \
        gload16(xh + gx, &Bh[SLOT][(size_t)tid * 8]);                              \
    }
#else
    #define QKV_STAGE(K0, SLOT) {                                                  \
        const size_t gw = (size_t)(ng0 + row) * HIDDEN + (K0) + (size_t)chS * 8;   \
        const size_t gx = (size_t)(m0 + row) * HIDDEN + (K0) + (size_t)chS * 8;    \
        *(f16x8*)&Ah[SLOT][(size_t)tid * 8] = *(const f16x8*)(wh + gw);            \
        *(f16x8*)&Al[SLOT][(size_t)tid * 8] = *(const f16x8*)(wl + gw);            \
        *(f16x8*)&Bh[SLOT][(size_t)tid * 8] = *(const f16x8*)(xh + gx);            \
    }
#endif

    QKV_STAGE(0, 0);
    QKV_STAGE(32, 1);

    for (int ks = 0; ks < 32; ++ks) {
        const int slot = ks % 3;
#if HAVE_GLL
        if (ks == 31) { asm volatile("s_waitcnt vmcnt(0)" ::: "memory"); }
        else          { asm volatile("s_waitcnt vmcnt(3)" ::: "memory"); }
        __builtin_amdgcn_s_barrier();
        asm volatile("" ::: "memory");      // fence: keep ds_reads below barrier
#else
        __syncthreads();
#endif
        {   // compute(ks): 32 MFMA / wave, product-major (r11/r12-validated)
            const ushort* pAh = Ah[slot];
            const ushort* pAl = Al[slot];
            const ushort* pBh = Bh[slot];
            f16x8 a_h[4], a_l[4], b_h[4];
            #pragma unroll
            for (int rf = 0; rf < 4; ++rf) {
                const int R = wr * 64 + rf * 16 + fr;
                a_h[rf] = *(const f16x8*)(pAh + R * 32 + cc);
                a_l[rf] = *(const f16x8*)(pAl + R * 32 + cc);
            }
            #pragma unroll
            for (int cf = 0; cf < 4; ++cf) {
                const int R = wc * 64 + cf * 16 + fr;
                b_h[cf] = *(const f16x8*)(pBh + R * 32 + cc);
            }
            #pragma unroll
            for (int rf = 0; rf < 4; ++rf)
                #pragma unroll
                for (int cf = 0; cf < 4; ++cf)
                    acc[rf][cf] = __builtin_amdgcn_mfma_f32_16x16x32_f16(a_h[rf], b_h[cf], acc[rf][cf], 0, 0, 0);
            #pragma unroll
            for (int rf = 0; rf < 4; ++rf)
                #pragma unroll
                for (int cf = 0; cf < 4; ++cf)
                    acc[rf][cf] = __builtin_amdgcn_mfma_f32_16x16x32_f16(a_l[rf], b_h[cf], acc[rf][cf], 0, 0, 0);
        }
        if (ks + 2 < 32) { QKV_STAGE((ks + 2) * 32, (ks + 2) % 3); }
#if !HAVE_GLL
        __syncthreads();
#endif
    }
    #undef QKV_STAGE

    // epilogue (validated r7-r12): row n_local = wr*64+rf*16+rq*4+r ; col m = wc*64+cf*16+fr
    const int rq = lane >> 4;
    #pragma unroll
    for (int rf = 0; rf < 4; ++rf) {
        #pragma unroll
        for (int r = 0; r < 4; ++r) {
            const int nl = wr * 64 + rf * 16 + rq * 4 + r;
            const float bv = bias[n0p + nl];
            float* dst = ct + (size_t)(n0p + nl) * M_TOTAL + m0 + wc * 64;
            #pragma unroll
            for (int cf = 0; cf < 4; ++cf)
                dst[cf * 16 + fr] = acc[rf][cf][r] + bv;
        }
    }
}

// ---------------------------------------------------------------------------
// Radix-16 FFT machinery (UNCHANGED, validated r5-r11 full-batch form)
// ---------------------------------------------------------------------------
__device__ __forceinline__ float2 cmul(float2 a, float2 b) {
    return {a.x*b.x - a.y*b.y, a.x*b.y + a.y*b.x};
}

__device__ __forceinline__ int phys(int p) { return p ^ ((p >> 4) & 15); }

template<int DIR>
__device__ __forceinline__ void dft16(const float2* x, float2* X) {
    float2 t[16];
    #pragma unroll
    for (int n0 = 0; n0 < 4; ++n0) {
        float2 a = x[n0], b = x[n0+4], c = x[n0+8], d = x[n0+12];
        float2 s0 = {a.x+c.x, a.y+c.y}, s1 = {a.x-c.x, a.y-c.y};
        float2 s2 = {b.x+d.x, b.y+d.y}, s3 = {b.x-d.x, b.y-d.y};
        t[n0*4+0] = {s0.x+s2.x, s0.y+s2.y};
        t[n0*4+2] = {s0.x-s2.x, s0.y-s2.y};
        if (DIR < 0) {
            t[n0*4+1] = {s1.x+s3.y, s1.y-s3.x};
            t[n0*4+3] = {s1.x-s3.y, s1.y+s3.x};
        } else {
            t[n0*4+1] = {s1.x-s3.y, s1.y+s3.x};
            t[n0*4+3] = {s1.x+s3.y, s1.y-s3.x};
        }
    }
    const float C1 = 0.92387953251128674f;
    const float S1_ = 0.38268343236508978f;
    const float R2 = 0.70710678118654752f;
    #define TW(idx, cc_, ss_) t[idx] = cmul(t[idx], (float2){cc_, DIR*(ss_)})
    TW(1*4+1, C1, S1_);   TW(1*4+2, R2, R2);    TW(1*4+3, S1_, C1);
    TW(2*4+1, R2, R2);    TW(2*4+2, 0.f, 1.f);  TW(2*4+3, -R2, R2);
    TW(3*4+1, S1_, C1);   TW(3*4+2, -R2, R2);   TW(3*4+3, -C1, -S1_);
    #undef TW
    #pragma unroll
    for (int k0 = 0; k0 < 4; ++k0) {
        float2 a = t[0+k0], b = t[4+k0], c = t[8+k0], d = t[12+k0];
        float2 s0 = {a.x+c.x, a.y+c.y}, s1 = {a.x-c.x, a.y-c.y};
        float2 s2 = {b.x+d.x, b.y+d.y}, s3 = {b.x-d.x, b.y-d.y};
        X[k0+0]  = {s0.x+s2.x, s0.y+s2.y};
        X[k0+8]  = {s0.x-s2.x, s0.y-s2.y};
        if (DIR < 0) {
            X[k0+4]  = {s1.x+s3.y, s1.y-s3.x};
            X[k0+12] = {s1.x-s3.y, s1.y+s3.x};
        } else {
            X[k0+4]  = {s1.x-s3.y, s1.y+s3.x};
            X[k0+12] = {s1.x+s3.y, s1.y-s3.x};
        }
    }
}

__device__ __forceinline__ void twiddle_apply(float2* y, float ang) {
    float s, c;
    __sincosf(ang, &s, &c);
    const float2 base = {c, s};
    float2 w = base;
    #pragma unroll
    for (int u = 1; u < 16; ++u) {
        y[u] = cmul(y[u], w);
        w = cmul(w, base);
    }
}

__global__ __launch_bounds__(256) void fft_attn_kernel(
    const float* __restrict__ qt, const float* __restrict__ kt,
    const float* __restrict__ vt, float* __restrict__ ot)
{
    __shared__ float2 bufA[FFT_N];
    __shared__ float2 bufB[FFT_N];

    const int tid = threadIdx.x;
    const int bid = blockIdx.x;
    const int n   = bid >> 2;
    const int b   = bid & 3;

    const size_t off = (size_t)n * M_TOTAL + (size_t)b * SEQ;
    const float* qrow = qt + off;
    const float* krow = kt + off;
    const float* vrow = vt + off;
    float*       orow = ot + off;

    {
        const int q = tid;
        float2 xA[16], xB[16], yA[16], yB[16];
        #pragma unroll
        for (int r = 0; r < 16; ++r) {
            xA[r] = { qrow[q + 256*r], krow[q + 256*r] };
            xB[r] = { vrow[q + 256*r], 0.f };
        }
        dft16<-1>(xA, yA);
        dft16<-1>(xB, yB);
        const float ang = -PI2 * (float)q / 4096.f;
        twiddle_apply(yA, ang);
        twiddle_apply(yB, ang);
        #pragma unroll
        for (int u = 0; u < 16; ++u) {
            bufA[phys(q + 256*u)] = yA[u];
            bufB[phys(q + 256*u)] = yB[u];
        }
    }
    __syncthreads();
    {
        const int blk = tid >> 4, a = tid & 15;
        const int base = 256*blk + a;
        float2 xA[16], xB[16], yA[16], yB[16];
        #pragma unroll
        for (int c = 0; c < 16; ++c) {
            xA[c] = bufA[phys(base + 16*c)];
            xB[c] = bufB[phys(base + 16*c)];
        }
        dft16<-1>(xA, yA);
        dft16<-1>(xB, yB);
        const float ang = -PI2 * (float)a / 256.f;
        twiddle_apply(yA, ang);
        twiddle_apply(yB, ang);
        #pragma unroll
        for (int c = 0; c < 16; ++c) {
            bufA[phys(base + 16*c)] = yA[c];
            bufB[phys(base + 16*c)] = yB[c];
        }
    }
    __syncthreads();
    {
        const int blk = tid >> 4, c = tid & 15;
        const int base = 256*blk + 16*c;
        float2 xA[16], xB[16], yA[16], yB[16];
        #pragma unroll
        for (int a2 = 0; a2 < 16; ++a2) {
            xA[a2] = bufA[phys(base + a2)];
            xB[a2] = bufB[phys(base + a2)];
        }
        dft16<-1>(xA, yA);
        dft16<-1>(xB, yB);
        #pragma unroll
        for (int d = 0; d < 16; ++d) {
            bufA[phys(base + d)] = yA[d];
            bufB[phys(base + d)] = yB[d];
        }
    }
    __syncthreads();
    #pragma unroll
    for (int it = 0; it < 16; ++it) {
        const int p  = tid + it * 256;
        const int j  = ((p & 15) << 8) | (p & 0xF0) | (p >> 8);
        const int jn = (FFT_N - j) & (FFT_N - 1);
        const int pn = ((jn & 15) << 8) | (jn & 0xF0) | (jn >> 8);
        const float2 Zj = bufA[phys(p)];
        const float2 Zn = bufA[phys(pn)];
        const float2 Q = { 0.5f*(Zj.x + Zn.x), 0.5f*(Zj.y - Zn.y) };
        const float2 K = { 0.5f*(Zj.y + Zn.y), -0.5f*(Zj.x - Zn.x) };
        const float2 G = { Q.x*K.x + Q.y*K.y, Q.y*K.x - Q.x*K.y };
        const float2 V = bufB[phys(p)];
        bufB[phys(p)] = { G.x*V.x - G.y*V.y, G.x*V.y + G.y*V.x };
    }
    __syncthreads();
    {
        const int blk = tid >> 4, c = tid & 15;
        const int base = 256*blk + 16*c;
        float2 x[16], y[16];
        #pragma unroll
        for (int d = 0; d < 16; ++d) x[d] = bufB[phys(base + d)];
        dft16<1>(x, y);
        #pragma unroll
        for (int p0 = 0; p0 < 16; ++p0) bufB[phys(base + p0)] = y[p0];
    }
    __syncthreads();
    {
        const int blk = tid >> 4, p0 = tid & 15;
        const int base = 256*blk + p0;
        float2 x[16], y[16];
        #pragma unroll
        for (int c = 0; c < 16; ++c) x[c] = bufB[phys(base + 16*c)];
        twiddle_apply(x, PI2 * (float)p0 / 256.f);
        dft16<1>(x, y);
        #pragma unroll
        for (int p1 = 0; p1 < 16; ++p1) bufB[phys(base + 16*p1)] = y[p1];
    }
    __syncthreads();
    {
        const int qq = tid;
        float2 x[16], y[16];
        #pragma unroll
        for (int t = 0; t < 16; ++t) x[t] = bufB[phys(qq + 256*t)];
        twiddle_apply(x, PI2 * (float)qq / 4096.f);
        dft16<1>(x, y);
        const float scale = 0.125f / 4096.f;
        #pragma unroll
        for (int p2 = 0; p2 < 16; ++p2)
            orow[qq + 256*p2] = y[p2].x * scale;
    }
}

// ---------------------------------------------------------------------------
// Transpose + fp16 split (r11-validated full-batch form)
// ---------------------------------------------------------------------------
__global__ __launch_bounds__(256) void transpose_split_kernel(
    const float* __restrict__ ot, ushort* __restrict__ oth,
    ushort* __restrict__ otl)
{
    __shared__ float tile[64][65];
    const int tid = threadIdx.x;
    const int m0  = blockIdx.x * 64;
    const int n0  = blockIdx.y * 64;
    const int r   = tid >> 4;
    const int c   = tid & 15;

    #pragma unroll
    for (int rr = 0; rr < 4; ++rr) {
        const int nl = r + rr * 16;
        float4 v = *(const float4*)(ot + (size_t)(n0 + nl) * M_TOTAL + m0 + c * 4);
        tile[nl][c * 4 + 0] = v.x; tile[nl][c * 4 + 1] = v.y;
        tile[nl][c * 4 + 2] = v.z; tile[nl][c * 4 + 3] = v.w;
    }
    __syncthreads();
    #pragma unroll
    for (int rr = 0; rr < 4; ++rr) {
        const int ml = r + rr * 16;
        ushort4 hh, ll;
        split1_f16(tile[c * 4 + 0][ml], hh.x, ll.x);
        split1_f16(tile[c * 4 + 1][ml], hh.y, ll.y);
        split1_f16(tile[c * 4 + 2][ml], hh.z, ll.z);
        split1_f16(tile[c * 4 + 3][ml], hh.w, ll.w);
        *(ushort4*)(oth + (size_t)(m0 + ml) * HIDDEN + n0 + c * 4) = hh;
        *(ushort4*)(otl + (size_t)(m0 + ml) * HIDDEN + n0 + c * 4) = ll;
    }
}

// ---------------------------------------------------------------------------
// Output GEMM (MFMA fp16, gload16 staging, triple-buffer + counted vmcnt)
// Grid 64 x 4 = 256 blocks (exactly one round).
// ---------------------------------------------------------------------------
__global__ __launch_bounds__(1024, 1) void gemm_out_mfma7(
    const ushort* __restrict__ oth, const ushort* __restrict__ otl,
    const ushort* __restrict__ woh, const float* __restrict__ bo,
    float* __restrict__ out)
{
    __shared__ ushort Ah[3][8192], Al[3][8192];   // ot^T tile [256m][32k] hi/lo
    __shared__ ushort Bh[3][8192];                // Wo tile [256n][32k] fp16

    const int tid  = threadIdx.x;
    const int lane = tid & 63;
    const int wid  = tid >> 6;
    const int wr   = wid >> 2;        // m-dim wave
    const int wc   = wid & 3;         // n-dim wave
    const int m0   = blockIdx.x * 256;
    const int n0   = blockIdx.y * 256;

    const int row = tid >> 2;
    const int chS = (tid & 3) ^ ((row >> 1) & 3);

    const int fr = lane & 15;
    const int fc = lane >> 4;
    const int cc = (fc ^ ((fr >> 1) & 3)) * 8;

    f32x4 acc[4][4];
    #pragma unroll
    for (int rf = 0; rf < 4; ++rf)
        #pragma unroll
        for (int cf = 0; cf < 4; ++cf)
            acc[rf][cf] = (f32x4){0.f, 0.f, 0.f, 0.f};

#if HAVE_GLL
    #define OUT_STAGE(K0, SLOT) {                                                  \
        const size_t ga = (size_t)(m0 + row) * HIDDEN + (K0) + (size_t)chS * 8;    \
        const size_t gb = (size_t)(n0 + row) * HIDDEN + (K0) + (size_t)chS * 8;    \
        gload16(oth + ga, &Ah[SLOT][(size_t)tid * 8]);                             \
        gload16(otl + ga, &Al[SLOT][(size_t)tid * 8]);                             \
        gload16(woh + gb, &Bh[SLOT][(size_t)tid * 8]);                             \
    }
#else
    #define OUT_STAGE(K0, SLOT) {                                                  \
        const size_t ga = (size_t)(m0 + row) * HIDDEN + (K0) + (size_t)chS * 8;    \
        const size_t gb = (size_t)(n0 + row) * HIDDEN + (K0) + (size_t)chS * 8;    \
        *(f16x8*)&Ah[SLOT][(size_t)tid * 8] = *(const f16x8*)(oth + ga);           \
        *(f16x8*)&Al[SLOT][(size_t)tid * 8] = *(const f16x8*)(otl + ga);           \
        *(f16x8*)&Bh[SLOT][(size_t)tid * 8] = *(const f16x8*)(woh + gb);           \
    }
#endif

    OUT_STAGE(0, 0);
    OUT_STAGE(32, 1);

    for (int ks = 0; ks < 32; ++ks) {
        const int slot = ks % 3;
#if HAVE_GLL
        if (ks == 31) { asm volatile("s_waitcnt vmcnt(0)" ::: "memory"); }
        else          { asm volatile("s_waitcnt vmcnt(3)" ::: "memory"); }
        __builtin_amdgcn_s_barrier();
        asm volatile("" ::: "memory");
#else
        __syncthreads();
#endif
        {
            const ushort* pAh = Ah[slot];
            const ushort* pAl = Al[slot];
            const ushort* pBh = Bh[slot];
            f16x8 a_h[4], a_l[4], b_h[4];
            #pragma unroll
            for (int rf = 0; rf < 4; ++rf) {
                const int R = wr * 64 + rf * 16 + fr;
                a_h[rf] = *(const f16x8*)(pAh + R * 32 + cc);
                a_l[rf] = *(const f16x8*)(pAl + R * 32 + cc);
            }
            #pragma unroll
            for (int cf = 0; cf < 4; ++cf) {
                const int R = wc * 64 + cf * 16 + fr;
                b_h[cf] = *(const f16x8*)(pBh + R * 32 + cc);
            }
            #pragma unroll
            for (int rf = 0; rf < 4; ++rf)
                #pragma unroll
                for (int cf = 0; cf < 4; ++cf)
                    acc[rf][cf] = __builtin_amdgcn_mfma_f32_16x16x32_f16(a_h[rf], b_h[cf], acc[rf][cf], 0, 0, 0);
            #pragma unroll
            for (int rf = 0; rf < 4; ++rf)
                #pragma unroll
                for (int cf = 0; cf < 4; ++cf)
                    acc[rf][cf] = __builtin_amdgcn_mfma_f32_16x16x32_f16(a_l[rf], b_h[cf], acc[rf][cf], 0, 0, 0);
        }
        if (ks + 2 < 32) { OUT_STAGE((ks + 2) * 32, (ks + 2) % 3); }
#if !HAVE_GLL
        __syncthreads();
#endif
    }
    #undef OUT_STAGE

    // epilogue: D row m_local = wr*64+rf*16+rq*4+r ; col n_local = wc*64+cf*16+fr
    const int rq = lane >> 4;
    float bo_v[4];
    #pragma unroll
    for (int cf = 0; cf < 4; ++cf) bo_v[cf] = bo[n0 + wc * 64 + cf * 16 + fr];
    #pragma unroll
    for (int rf = 0; rf < 4; ++rf) {
        #pragma unroll
        for (int r = 0; r < 4; ++r) {
            const int ml = wr * 64 + rf * 16 + rq * 4 + r;
            float* dst = out + (size_t)(m0 + ml) * HIDDEN + n0 + wc * 64;
            #pragma unroll
            for (int cf = 0; cf < 4; ++cf)
                dst[cf * 16 + fr] = acc[rf][cf][r] + bo_v[cf];
        }
    }
}

// ---------------------------------------------------------------------------
// Buffers (ws = proven 201.3 MB; fp16 operand planes stashed in d_out):
//   ws:    qt/kt/vt fp32 full planes (67.1 MB each).
//   d_out: xh fp16 [16384][1024] @0 (33.55 MB), wh @33.55 (6.29), wl @39.84
//          (6.29) -- dead once qkv completes; gemm_out then overwrites d_out.
//   After fft: kt plane -> oth+otl (33.55+33.55 = 67.1 exact); vt plane ->
//   woh (2.1 MB, re-converted post-fft since vt is live earlier).
//   ot aliases qt (in-place FFT write, validated r3-r11).
// ---------------------------------------------------------------------------
extern "C" void kernel_launch(void* const* d_in, const int* in_sizes, int n_in,
                              void* d_out, int out_size, void* d_ws, size_t ws_size,
                              hipStream_t stream)
{
    const float* x  = (const float*)d_in[0];
    const float* Wq = (const float*)d_in[1];
    const float* bq = (const float*)d_in[2];
    const float* Wk = (const float*)d_in[3];
    const float* bk = (const float*)d_in[4];
    const float* Wv = (const float*)d_in[5];
    const float* bv = (const float*)d_in[6];
    const float* Wo = (const float*)d_in[7];
    const float* bo = (const float*)d_in[8];
    float* out = (float*)d_out;

    const size_t plane = (size_t)HIDDEN * M_TOTAL;   // 16.78M elements
    float* qt = (float*)d_ws;
    float* kt = qt + plane;
    float* vt = kt + plane;
    float* ot = qt;                     // FFT output aliases q plane

    // fp16 operand stash in d_out (dead until gemm_out overwrites it)
    ushort* xh = (ushort*)d_out;                    // [16384][1024]
    ushort* wh = xh + plane;                        // stacked [3072][1024]
    ushort* wl = wh + 3 * WSZ;

    // post-fft stash in dead ws planes
    ushort* oth = (ushort*)kt;                      // [16384][1024] fp16 hi
    ushort* otl = oth + plane;                      // lo (ends exactly at vt)
    ushort* woh = (ushort*)vt;                      // [1024][1024] fp16

    // pre-passes: x -> fp16; Wq/Wk/Wv -> fp16 hi/lo (into d_out stash)
    cvt16_kernel<<<(unsigned)(plane / 2048), 256, 0, stream>>>(x, xh);
    split16_kernel<<<(unsigned)(WSZ / 2048), 256, 0, stream>>>(Wq, wh, wl);
    split16_kernel<<<(unsigned)(WSZ / 2048), 256, 0, stream>>>(Wk, wh + WSZ, wl + WSZ);
    split16_kernel<<<(unsigned)(WSZ / 2048), 256, 0, stream>>>(Wv, wh + 2 * WSZ, wl + 2 * WSZ);

    // QKV projections (full batch, 768 blocks = 3x256)
    gemm_qkv_mfma7<<<dim3(M_TOTAL / 256, 12), 1024, 0, stream>>>(
        xh, wh, wl, bq, bk, bv, qt);

    // FFT attention (full batch, writes ot = qt in place)
    fft_attn_kernel<<<dim3(HIDDEN * BATCH), 256, 0, stream>>>(qt, kt, vt, ot);

    // Wo -> fp16 into dead vt plane
    cvt16_kernel<<<(unsigned)(WSZ / 2048), 256, 0, stream>>>(Wo, woh);

    // transpose ot -> fp16 hi/lo [m][k] into dead kt plane
    transpose_split_kernel<<<dim3(M_TOTAL / 64, HIDDEN / 64), 256, 0, stream>>>(
        ot, oth, otl);

    // output projection (256 blocks, overwrites d_out)
    gemm_out_mfma7<<<dim3(M_TOTAL / 256, HIDDEN / 256), 1024, 0, stream>>>(
        oth, otl, woh, bo, out);
}